// Round 4
// baseline (218.267 us; speedup 1.0000x reference)
//
#include <hip/hip_runtime.h>
#include <hip/hip_fp16.h>

#define OUTN 16384
#define BATCH 2048
#define DIM   256

typedef _Float16 half8 __attribute__((ext_vector_type(8)));
typedef float    floatx4 __attribute__((ext_vector_type(4)));
typedef unsigned long long u64;

__device__ __forceinline__ void gl2lds16(const void* g, void* l) {
    __builtin_amdgcn_global_load_lds(
        (const __attribute__((address_space(1))) void*)g,
        (__attribute__((address_space(3))) void*)l, 16, 0, 0);
}

// monotone float->uint map packed with column index (low 32): min(pack) = argmin
__device__ __forceinline__ u64 packkey(float v, int col) {
    unsigned u = __float_as_uint(v);
    u = (u & 0x80000000u) ? ~u : (u | 0x80000000u);
    return ((u64)u << 32) | (unsigned)col;
}
__device__ __forceinline__ float unpackval(u64 p) {
    unsigned u = (unsigned)(p >> 32);
    u = (u & 0x80000000u) ? (u & 0x7fffffffu) : ~u;
    return __uint_as_float(u);
}

// ---------------- P0 fused prep ----------------
// blocks [0,512): transpose kern -> kT (f16) + kT32 (fp32) + fp32 col-norm halves
// blocks [512,2560): x -> f16 + row norms
__global__ __launch_bounds__(256) void prep_all(
        const float* __restrict__ x, const float* __restrict__ kern,
        _Float16* __restrict__ xh, float* __restrict__ rown,
        _Float16* __restrict__ kT, float* __restrict__ kT32,
        float* __restrict__ colnp) {
    int blk = blockIdx.x, t = threadIdx.x;
    if (blk < 512) {
        __shared__ float tile[64][65];
        __shared__ float npart[4][64];
        int tx = t & 63, ty = t >> 6;
        int j0 = (blk >> 1) * 64;
        int dhalf = blk & 1, dbase = dhalf * 128;
        float nrm = 0.f;
        for (int pc = 0; pc < 2; pc++) {
            int dc = dbase + pc * 64;
            __syncthreads();
            for (int it = 0; it < 16; it++) {
                int d = dc + ty + it * 4;
                float v = kern[(size_t)d * OUTN + j0 + tx];
                tile[ty + it * 4][tx] = v;
                nrm = fmaf(v, v, nrm);
            }
            __syncthreads();
            for (int c = t; c < 512; c += 256) {   // 64j x 64d out, 8-elem chunks
                int j = c >> 3, o8 = (c & 7) * 8;
                half8 h;
                float4 f0, f1;
                float vv[8];
                for (int u = 0; u < 8; u++) { vv[u] = tile[o8 + u][j]; h[u] = (_Float16)vv[u]; }
                f0 = make_float4(vv[0], vv[1], vv[2], vv[3]);
                f1 = make_float4(vv[4], vv[5], vv[6], vv[7]);
                *(half8*)&kT[(size_t)(j0 + j) * DIM + dc + o8] = h;
                float* kp = &kT32[(size_t)(j0 + j) * DIM + dc + o8];
                *(float4*)kp = f0;
                *(float4*)(kp + 4) = f1;
            }
        }
        npart[ty][tx] = nrm;
        __syncthreads();
        if (t < 64)
            colnp[(size_t)dhalf * OUTN + j0 + t] =
                npart[0][t] + npart[1][t] + npart[2][t] + npart[3][t];
    } else {
        int b = blk - 512;                         // 2048 rows
        float v = x[b * DIM + t];
        xh[b * DIM + t] = (_Float16)v;
        float s = v * v;
        for (int off = 32; off; off >>= 1) s += __shfl_down(s, off, 64);
        __shared__ float wsum[4];
        if ((t & 63) == 0) wsum[t >> 6] = s;
        __syncthreads();
        if (t == 0) rown[b] = wsum[0] + wsum[1] + wsum[2] + wsum[3];
    }
}

// ---------------- P1: GEMM pass A -> per-(row,128col) top-2 candidates only ----------------
__global__ __launch_bounds__(256) void gemm_cand(
        const _Float16* __restrict__ xh, const _Float16* __restrict__ kT,
        const float* __restrict__ colnp, u64* __restrict__ blockcand) {
    __shared__ __align__(16) char smem[32768];
    _Float16* As = (_Float16*)smem;                // 128 x 64, 16B-granule XOR swizzle
    _Float16* Bs = (_Float16*)(smem + 16384);
    u64* cand = (u64*)smem;                        // 128 x 32, reused after k-loop
    int tid  = threadIdx.x;
    int col0 = blockIdx.x * 128;
    int row0 = blockIdx.y * 128;
    int wid = tid >> 6, lane = tid & 63;
    int wr = wid >> 1, wc = wid & 1;
    int l15 = lane & 15, l4 = lane >> 4;
    int xh7 = l15 & 7;

    floatx4 acc[4][4];
    for (int i = 0; i < 4; i++)
        for (int j = 0; j < 4; j++)
            acc[i][j] = (floatx4){0.f, 0.f, 0.f, 0.f};

    for (int kt = 0; kt < 4; kt++) {
        int k0 = kt * 64;
        for (int it = 0; it < 4; it++) {
            int chunk = it * 256 + tid;
            int r = chunk >> 3, gg = chunk & 7;
            int ksw = (gg ^ (r & 7)) * 8;
            gl2lds16(&xh[(size_t)(row0 + r) * DIM + k0 + ksw], &As[chunk * 8]);
            gl2lds16(&kT[(size_t)(col0 + r) * DIM + k0 + ksw], &Bs[chunk * 8]);
        }
        __syncthreads();
        for (int s = 0; s < 2; s++) {
            int g = s * 4 + l4;
            int sw = (g ^ xh7) * 8;
            half8 af[4], bf[4];
            for (int i = 0; i < 4; i++)
                af[i] = *(half8*)&As[(wr * 64 + i * 16 + l15) * 64 + sw];
            for (int j = 0; j < 4; j++)
                bf[j] = *(half8*)&Bs[(wc * 64 + j * 16 + l15) * 64 + sw];
            for (int i = 0; i < 4; i++)
                for (int j = 0; j < 4; j++)
                    acc[i][j] = __builtin_amdgcn_mfma_f32_16x16x32_f16(
                        af[i], bf[j], acc[i][j], 0, 0, 0);
        }
        __syncthreads();
    }

    // key = coln - 2*dot (row-constant ||x||^2 dropped; argmin per row unchanged)
    float cn[4]; int oc[4];
    for (int j = 0; j < 4; j++) {
        oc[j] = col0 + wc * 64 + j * 16 + l15;
        cn[j] = colnp[oc[j]] + colnp[OUTN + oc[j]];
    }
    for (int i = 0; i < 4; i++) {
        for (int r = 0; r < 4; r++) {
            int row_l = wr * 64 + i * 16 + l4 * 4 + r;
            u64 best = ~0ull;
            for (int j = 0; j < 4; j++) {
                u64 p = packkey(cn[j] - 2.0f * acc[i][j][r], oc[j]);
                if (p < best) best = p;
            }
            cand[row_l * 32 + wc * 16 + l15] = best;
        }
    }
    __syncthreads();
    if (tid < 128) {
        u64 m1 = ~0ull, m2 = ~0ull;
        for (int s = 0; s < 32; s++) {
            u64 v = cand[tid * 32 + s];
            if (v < m1) { m2 = m1; m1 = v; }
            else if (v < m2) { m2 = v; }
        }
        size_t base = (size_t)(row0 + tid) * 256 + blockIdx.x * 2;
        blockcand[base]     = m1;
        blockcand[base + 1] = m2;
    }
}

// ---------------- P2: candidate argmin refinement (exact fp32, contiguous kT32) -> wta ----
__global__ __launch_bounds__(256) void refine(
        const u64* __restrict__ blockcand, const float* __restrict__ x,
        const float* __restrict__ kT32, const float* __restrict__ colnp,
        int* __restrict__ wta) {
    int b = blockIdx.x, t = threadIdx.x;           // 2048 x 256
    __shared__ float xrow[DIM];
    __shared__ u64 red[256];
    xrow[t] = x[b * DIM + t];
    u64 e = blockcand[(size_t)b * 256 + t];
    red[t] = e;
    __syncthreads();
    for (int off = 128; off; off >>= 1) {
        if (t < off) { u64 o = red[t + off]; if (o < red[t]) red[t] = o; }
        __syncthreads();
    }
    float minv = unpackval(red[0]);
    __syncthreads();

    u64 p = ~0ull;
    if (unpackval(e) <= minv + 0.125f) {
        int j = (int)(e & 0xffffffffu);
        const float* kr = kT32 + (size_t)j * DIM;  // contiguous fp32 row
        float dot = 0.f;
        for (int d = 0; d < DIM; d++)
            dot = fmaf(xrow[d], kr[d], dot);
        p = packkey((colnp[j] + colnp[OUTN + j]) - 2.0f * dot, j);
    }
    red[t] = p;
    __syncthreads();
    for (int off = 128; off; off >>= 1) {
        if (t < off) { u64 o = red[t + off]; if (o < red[t]) red[t] = o; }
        __syncthreads();
    }
    if (t == 0) wta[b] = (int)(red[0] & 0xffffffffu);
}

// ---------------- P3: GEMM pass B -> gaussian * norms2, coalesced fp32 out ----------------
__global__ __launch_bounds__(256) void gemm_out(
        const _Float16* __restrict__ xh, const _Float16* __restrict__ kT,
        const float* __restrict__ rown, const float* __restrict__ colnp,
        const int* __restrict__ wta, float* __restrict__ out) {
    __shared__ __align__(16) char smem[32768];
    _Float16* As = (_Float16*)smem;
    _Float16* Bs = (_Float16*)(smem + 16384);
    float* buf = (float*)smem;                     // 64 x 128 fp32, reused after k-loop
    __shared__ int   wtal[128];
    __shared__ float rnl[128];
    __shared__ float colf[128];
    int tid  = threadIdx.x;
    int col0 = blockIdx.x * 128;                   // col-block == grid row (SIDE=128)
    int row0 = blockIdx.y * 128;
    int wid = tid >> 6, lane = tid & 63;
    int wr = wid >> 1, wc = wid & 1;
    int l15 = lane & 15, l4 = lane >> 4;
    int xh7 = l15 & 7;

    if (tid < 128) {
        wtal[tid] = wta[row0 + tid];
        rnl[tid]  = rown[row0 + tid];
        colf[tid] = __expf(-0.125f * (float)(tid * tid));
    }

    floatx4 acc[4][4];
    for (int i = 0; i < 4; i++)
        for (int j = 0; j < 4; j++)
            acc[i][j] = (floatx4){0.f, 0.f, 0.f, 0.f};

    for (int kt = 0; kt < 4; kt++) {
        int k0 = kt * 64;
        for (int it = 0; it < 4; it++) {
            int chunk = it * 256 + tid;
            int r = chunk >> 3, gg = chunk & 7;
            int ksw = (gg ^ (r & 7)) * 8;
            gl2lds16(&xh[(size_t)(row0 + r) * DIM + k0 + ksw], &As[chunk * 8]);
            gl2lds16(&kT[(size_t)(col0 + r) * DIM + k0 + ksw], &Bs[chunk * 8]);
        }
        __syncthreads();
        for (int s = 0; s < 2; s++) {
            int g = s * 4 + l4;
            int sw = (g ^ xh7) * 8;
            half8 af[4], bf[4];
            for (int i = 0; i < 4; i++)
                af[i] = *(half8*)&As[(wr * 64 + i * 16 + l15) * 64 + sw];
            for (int j = 0; j < 4; j++)
                bf[j] = *(half8*)&Bs[(wc * 64 + j * 16 + l15) * 64 + sw];
            for (int i = 0; i < 4; i++)
                for (int j = 0; j < 4; j++)
                    acc[i][j] = __builtin_amdgcn_mfma_f32_16x16x32_f16(
                        af[i], bf[j], acc[i][j], 0, 0, 0);
        }
        __syncthreads();
    }

    // epilogue: gauss(d2) * max(norms2,0); gauss = colf[|dr|]*colf[|dc|]
    float cn[4]; int gcj[4];
    for (int j = 0; j < 4; j++) {
        int oc = col0 + wc * 64 + j * 16 + l15;
        cn[j]  = colnp[oc] + colnp[OUTN + oc];
        gcj[j] = oc & 127;
    }
    for (int h = 0; h < 2; h++) {                  // 64-row halves through LDS
        if (wr == h) {
            for (int i = 0; i < 4; i++) {
                for (int r = 0; r < 4; r++) {
                    int row_l = i * 16 + l4 * 4 + r;       // within this half
                    float rn = rnl[h * 64 + row_l];
                    int w = wtal[h * 64 + row_l];
                    int dr = blockIdx.x - (w >> 7); dr = dr < 0 ? -dr : dr;
                    float rowf = colf[dr];
                    int wcc = w & 127;
                    for (int j = 0; j < 4; j++) {
                        int dc = gcj[j] - wcc; dc = dc < 0 ? -dc : dc;
                        float val = rn + cn[j] - 2.0f * acc[i][j][r];
                        buf[row_l * 128 + wc * 64 + j * 16 + l15] =
                            rowf * colf[dc] * fmaxf(val, 0.f);
                    }
                }
            }
        }
        __syncthreads();
        for (int q = tid; q < 2048; q += 256) {    // 64x128 fp32 as float4 stores
            int rr = q >> 5, cc = (q & 31) * 4;
            *(float4*)&out[(size_t)(row0 + h * 64 + rr) * OUTN + col0 + cc] =
                *(float4*)&buf[rr * 128 + cc];
        }
        __syncthreads();
    }
}

extern "C" void kernel_launch(void* const* d_in, const int* in_sizes, int n_in,
                              void* d_out, int out_size, void* d_ws, size_t ws_size,
                              hipStream_t stream) {
    const float* x    = (const float*)d_in[0];   // (2048, 256) fp32
    const float* kern = (const float*)d_in[1];   // (256, 16384) fp32
    float* out = (float*)d_out;                  // (2048, 16384) fp32
    char* ws = (char*)d_ws;

    // ws (~30 MB): xh 1MB | kT 8MB | kT32 16MB | colnp 128K | rown 8K | wta 8K | blockcand 4MB
    _Float16* xh   = (_Float16*)(ws);
    _Float16* kT   = (_Float16*)(ws + (1u << 20));
    float*    kT32 = (float*)(ws + (9u << 20));
    float*   colnp = (float*)(ws + (25u << 20));
    float*    rown = (float*)(ws + (25u << 20) + (128u << 10));
    int*       wta = (int*)(ws + (25u << 20) + (136u << 10));
    u64* blockcand = (u64*)(ws + (26u << 20));

    prep_all<<<2560, 256, 0, stream>>>(x, kern, xh, rown, kT, kT32, colnp);
    gemm_cand<<<dim3(OUTN / 128, BATCH / 128), 256, 0, stream>>>(xh, kT, colnp, blockcand);
    refine<<<BATCH, 256, 0, stream>>>(blockcand, x, kT32, colnp, wta);
    gemm_out<<<dim3(OUTN / 128, BATCH / 128), 256, 0, stream>>>(xh, kT, rown, colnp, wta, out);
}